// Round 4
// baseline (771.501 us; speedup 1.0000x reference)
//
#include <hip/hip_runtime.h>

typedef short bf16x8 __attribute__((ext_vector_type(8)));
typedef float f32x4 __attribute__((ext_vector_type(4)));

#define AS1 __attribute__((address_space(1)))
#define AS3 __attribute__((address_space(3)))

// async global->LDS, 16B per lane (used by GEMM only).
__device__ __forceinline__ void async16(const void* g, void* l) {
    __builtin_amdgcn_global_load_lds((AS1 unsigned*)(unsigned long long)g,
                                     (AS3 unsigned*)l, 16, 0, 0);
}

__device__ __forceinline__ unsigned short f2bf(float f) {
    unsigned u = __builtin_bit_cast(unsigned, f);
    u += 0x7fffu + ((u >> 16) & 1u);   // RNE
    return (unsigned short)(u >> 16);
}
__device__ __forceinline__ float bf2f(unsigned short s) {
    unsigned u = ((unsigned)s) << 16;
    return __builtin_bit_cast(float, u);
}

// ---------------- LayerNorm + bf16 cast: one wave per row of 512 ----------------
__global__ __launch_bounds__(256) void ln_bf16_kernel(
    const float* __restrict__ x, const float* __restrict__ gamma,
    const float* __restrict__ beta, unsigned short* __restrict__ xn, int nrows)
{
    int row = blockIdx.x * 4 + (threadIdx.x >> 6);
    int lane = threadIdx.x & 63;
    if (row >= nrows) return;
    const float4* xr = (const float4*)(x + (size_t)row * 512);
    float4 a = xr[lane], b = xr[lane + 64];
    float s = a.x + a.y + a.z + a.w + b.x + b.y + b.z + b.w;
    #pragma unroll
    for (int m = 1; m < 64; m <<= 1) s += __shfl_xor(s, m);
    float mu = s * (1.0f / 512.0f);
    float dx[8] = {a.x - mu, a.y - mu, a.z - mu, a.w - mu,
                   b.x - mu, b.y - mu, b.z - mu, b.w - mu};
    float ss = 0.f;
    #pragma unroll
    for (int i = 0; i < 8; ++i) ss += dx[i] * dx[i];
    #pragma unroll
    for (int m = 1; m < 64; m <<= 1) ss += __shfl_xor(ss, m);
    float rstd = rsqrtf(ss * (1.0f / 512.0f) + 1e-5f);
    const float4* gp = (const float4*)gamma;
    const float4* bp = (const float4*)beta;
    float4 g0 = gp[lane], g1 = gp[lane + 64], b0 = bp[lane], b1 = bp[lane + 64];
    float y[8];
    y[0] = dx[0] * rstd * g0.x + b0.x; y[1] = dx[1] * rstd * g0.y + b0.y;
    y[2] = dx[2] * rstd * g0.z + b0.z; y[3] = dx[3] * rstd * g0.w + b0.w;
    y[4] = dx[4] * rstd * g1.x + b1.x; y[5] = dx[5] * rstd * g1.y + b1.y;
    y[6] = dx[6] * rstd * g1.z + b1.z; y[7] = dx[7] * rstd * g1.w + b1.w;
    ushort4* orow = (ushort4*)(xn + (size_t)row * 512);
    orow[lane]      = make_ushort4(f2bf(y[0]), f2bf(y[1]), f2bf(y[2]), f2bf(y[3]));
    orow[lane + 64] = make_ushort4(f2bf(y[4]), f2bf(y[5]), f2bf(y[6]), f2bf(y[7]));
}

// ------------- fp32 [R][C] -> bf16 transposed [C][R] (for weights) -------------
__global__ __launch_bounds__(256) void transpose_w(
    const float* __restrict__ in, unsigned short* __restrict__ outT, int R, int Cd)
{
    __shared__ float tile[64][65];
    int r0 = blockIdx.x * 64, c0 = blockIdx.y * 64;
    int lr = threadIdx.x >> 6, lc = threadIdx.x & 63;
    #pragma unroll
    for (int i = 0; i < 16; ++i) {
        int r = i * 4 + lr;
        tile[r][lc] = in[(size_t)(r0 + r) * Cd + c0 + lc];
    }
    __syncthreads();
    #pragma unroll
    for (int i = 0; i < 16; ++i) {
        int r = i * 4 + lr;
        outT[(size_t)(c0 + r) * R + r0 + lc] = f2bf(tile[lc][r]);
    }
}

// ---- vraw[b*4096+t][512] -> tile-packed Vt: vtp[b][t/32][c][t%32] (bf16) ----
__global__ __launch_bounds__(256) void transpose_v(
    const unsigned short* __restrict__ vraw, unsigned short* __restrict__ vtp)
{
    __shared__ unsigned short tile[64][72];
    int b = blockIdx.z;
    int t0 = blockIdx.x * 64, c0 = blockIdx.y * 64;
    int lr = threadIdx.x >> 6, lc = threadIdx.x & 63;
    const unsigned short* src = vraw + (size_t)(b * 4096 + t0) * 512 + c0;
    #pragma unroll
    for (int i = 0; i < 16; ++i) {
        int r = i * 4 + lr;
        tile[r][lc] = src[(size_t)r * 512 + lc];
    }
    __syncthreads();
    #pragma unroll
    for (int i = 0; i < 16; ++i) {
        int r = i * 4 + lr;           // c_local
        int jt = (t0 >> 5) + (lc >> 5);
        int tl = lc & 31;
        vtp[(((size_t)(b * 128 + jt)) * 512 + c0 + r) * 32 + tl] = tile[lc][r];
    }
}

// ---------------- GEMM: C[M,N] = A[M,K] * Bt[N,K]^T, bf16 MFMA ----------------
__global__ __launch_bounds__(256) void gemm_bt(
    const unsigned short* __restrict__ A, const unsigned short* __restrict__ Bt,
    void* __restrict__ Cp, int M, int N, int K, int lda, int ldb, int ldc, int outBf16)
{
    __shared__ unsigned short As[128 * 64];
    __shared__ unsigned short Bs[128 * 64];
    const int tid = threadIdx.x;
    const int w = tid >> 6, lane = tid & 63, quad = lane >> 4, l15 = lane & 15;
    const int wm = w >> 1, wn = w & 1;
    const size_t m0 = (size_t)blockIdx.x * 128, n0 = (size_t)blockIdx.y * 128;
    f32x4 zero = {0.f, 0.f, 0.f, 0.f};
    f32x4 acc[4][4];
    #pragma unroll
    for (int i = 0; i < 4; ++i)
        #pragma unroll
        for (int j = 0; j < 4; ++j) acc[i][j] = zero;

    for (int k0 = 0; k0 < K; k0 += 64) {
        __syncthreads();
        #pragma unroll
        for (int r = 0; r < 4; ++r) {
            int s = r * 256 + w * 64 + lane;
            int row = s >> 3, x = s & 7, g = x ^ (row & 7);
            async16(A + (m0 + row) * lda + k0 + g * 8,
                    (char*)As + (size_t)(r * 256 + w * 64) * 16);
        }
        #pragma unroll
        for (int r = 0; r < 4; ++r) {
            int s = r * 256 + w * 64 + lane;
            int row = s >> 3, x = s & 7, g = x ^ (row & 7);
            async16(Bt + (n0 + row) * ldb + k0 + g * 8,
                    (char*)Bs + (size_t)(r * 256 + w * 64) * 16);
        }
        __syncthreads();
        #pragma unroll
        for (int ks = 0; ks < 2; ++ks) {
            bf16x8 af[4], bf[4];
            int cc = ks * 4 + quad;
            #pragma unroll
            for (int mt = 0; mt < 4; ++mt) {
                int row = wm * 64 + mt * 16 + l15;
                int x = cc ^ (row & 7);
                af[mt] = *(const bf16x8*)(As + row * 64 + x * 8);
            }
            #pragma unroll
            for (int nt = 0; nt < 4; ++nt) {
                int row = wn * 64 + nt * 16 + l15;
                int x = cc ^ (row & 7);
                bf[nt] = *(const bf16x8*)(Bs + row * 64 + x * 8);
            }
            #pragma unroll
            for (int mt = 0; mt < 4; ++mt)
                #pragma unroll
                for (int nt = 0; nt < 4; ++nt)
                    acc[mt][nt] = __builtin_amdgcn_mfma_f32_16x16x32_bf16(
                        af[mt], bf[nt], acc[mt][nt], 0, 0, 0);
        }
    }
    #pragma unroll
    for (int mt = 0; mt < 4; ++mt)
        #pragma unroll
        for (int nt = 0; nt < 4; ++nt)
            #pragma unroll
            for (int r = 0; r < 4; ++r) {
                size_t grow = m0 + wm * 64 + mt * 16 + quad * 4 + r;
                size_t gcol = n0 + wn * 64 + nt * 16 + l15;
                float v = acc[mt][nt][r];
                if (outBf16) ((unsigned short*)Cp)[grow * ldc + gcol] = f2bf(v);
                else         ((float*)Cp)[grow * ldc + gcol] = v;
            }
}

// ---------------- Flash attention v4: balanced halves + reg-prefetch ----------------
// 4 waves, q-tile 64 (16 q-rows/wave), j-tile 32. Block handles HALF the j-range
// of q-tile qa AND half of (63-qa): exactly 65 j-tiles per block (perfect balance).
// No-max softmax (scores ~N(0,1)) => halves combine linearly: unnormalized O (bf16)
// + row-sum l written per half; combine kernel divides.
// Staging: global->VGPR prefetch of next tile during compute, ds_write at tile top
// (compiler's use-site vmcnt gives real overlap -- global_load_lds cannot).
__global__ __launch_bounds__(256, 1) void attn_kernel(
    const unsigned short* __restrict__ qk,    // [b*4096+t][1024] : Q | K
    const unsigned short* __restrict__ vtp,   // [b][t/32][c][t%32]
    unsigned short* __restrict__ ph0, unsigned short* __restrict__ ph1,
    float* __restrict__ lp)                   // [2][16384]
{
    __shared__ unsigned short Ks[32 * 512];   // 32 KB, XOR chunk swizzle
    __shared__ unsigned short Vs[512 * 40];   // 40 KB: 4 chunks + 1 pad chunk per c-row
    __shared__ unsigned short Ps[4 * 16 * 40];// per-wave P, stride 40

    const int id = blockIdx.x;
    const int b = id & 3, p = id >> 2;
    const int qa = p >> 1, h = p & 1;

    const int tid = threadIdx.x, w = tid >> 6, lane = tid & 63;
    const int quad = lane >> 4, l15 = lane & 15;
    const float scale = 0.04419417382415922f;  // 1/sqrt(512)
    f32x4 zero = {0.f, 0.f, 0.f, 0.f};

    const unsigned short* kbase = qk + (size_t)(b * 4096) * 1024 + 512;
    const unsigned short* vbase = vtp + (size_t)(b * 128) * 16384;
    unsigned short* dst = h ? ph1 : ph0;

    float4 kreg[8], vreg[8];

    #pragma unroll
    for (int job = 0; job < 2; ++job) {
        const int q = job ? (63 - qa) : qa;
        const int jt0 = h ? (q + 1) : 0;
        const int jtN = h ? (2 * q + 2) : (q + 1);

        // Q fragments: A[m=l15][k=quad*8+j], 16 k-steps of 32
        bf16x8 qf[16];
        {
            const unsigned short* qb =
                qk + (size_t)(b * 4096 + q * 64 + w * 16 + l15) * 1024;
            #pragma unroll
            for (int ks = 0; ks < 16; ++ks)
                qf[ks] = *(const bf16x8*)(qb + ks * 32 + quad * 8);
        }
        f32x4 o[32];
        #pragma unroll
        for (int i = 0; i < 32; ++i) o[i] = zero;
        float li[4] = {0.f, 0.f, 0.f, 0.f};

        // prefetch first tile into registers
        {
            const unsigned short* kg = kbase + (size_t)jt0 * 32 * 1024;
            const unsigned short* vg = vbase + (size_t)jt0 * 16384;
            #pragma unroll
            for (int i = 0; i < 8; ++i) {
                int s = i * 256 + tid;
                int row = s >> 6, x = s & 63, g = (x & ~7) | ((x ^ row) & 7);
                kreg[i] = *(const float4*)(kg + row * 1024 + g * 8);
                vreg[i] = *(const float4*)(vg + s * 8);
            }
        }

        for (int jt = jt0; jt < jtN; ++jt) {
            __syncthreads();   // all waves done reading previous tile
            #pragma unroll
            for (int i = 0; i < 8; ++i) {
                int s = i * 256 + tid;
                *(float4*)(Ks + (size_t)s * 8) = kreg[i];          // slot = (row,x)
                int c = s >> 2, x = s & 3;
                *(float4*)(Vs + (size_t)c * 40 + x * 8) = vreg[i]; // padded stride
            }
            __syncthreads();   // staged tile visible

            // prefetch next tile (global->reg; latency hides under compute)
            if (jt + 1 < jtN) {
                const unsigned short* kg = kbase + (size_t)(jt + 1) * 32 * 1024;
                const unsigned short* vg = vbase + (size_t)(jt + 1) * 16384;
                #pragma unroll
                for (int i = 0; i < 8; ++i) {
                    int s = i * 256 + tid;
                    int row = s >> 6, x = s & 63, g = (x & ~7) | ((x ^ row) & 7);
                    kreg[i] = *(const float4*)(kg + row * 1024 + g * 8);
                    vreg[i] = *(const float4*)(vg + s * 8);
                }
            }

            // S = Q K^T  (16q x 32j per wave)
            f32x4 sa[2];
            sa[0] = zero; sa[1] = zero;
            #pragma unroll
            for (int ks = 0; ks < 16; ++ks) {
                int cc = ks * 4 + quad;
                #pragma unroll
                for (int nt = 0; nt < 2; ++nt) {
                    int jr = nt * 16 + l15;
                    int xg = (cc & ~7) | ((cc ^ jr) & 7);
                    bf16x8 kf = *(const bf16x8*)(Ks + jr * 512 + xg * 8);
                    sa[nt] = __builtin_amdgcn_mfma_f32_16x16x32_bf16(
                        qf[ks], kf, sa[nt], 0, 0, 0);
                }
            }
            // lane-local softmax accumulate; unconditional causal mask
            const int trow = q * 64 + w * 16 + quad * 4;
            #pragma unroll
            for (int r = 0; r < 4; ++r) {
                #pragma unroll
                for (int nt = 0; nt < 2; ++nt) {
                    int col = jt * 32 + nt * 16 + l15;
                    float sv = sa[nt][r] * scale;
                    float pv = __expf(fminf(sv, 60.f));
                    if (col > trow + r) pv = 0.f;
                    li[r] += pv;
                    Ps[w * 640 + (quad * 4 + r) * 40 + nt * 16 + l15] = f2bf(pv);
                }
            }
            // O += P V : one k-step of 32 covers the j-tile
            bf16x8 pf = *(const bf16x8*)(Ps + w * 640 + l15 * 40 + quad * 8);
            #pragma unroll
            for (int ct = 0; ct < 32; ++ct) {
                int c = ct * 16 + l15;
                bf16x8 vf = *(const bf16x8*)(Vs + c * 40 + quad * 8);
                o[ct] = __builtin_amdgcn_mfma_f32_16x16x32_bf16(pf, vf, o[ct], 0, 0, 0);
            }
        }

        // row-sum reduction (16 lanes per quad-row) + partial store (unnormalized)
        #pragma unroll
        for (int r = 0; r < 4; ++r) {
            float s = li[r];
            s += __shfl_xor(s, 1);
            s += __shfl_xor(s, 2);
            s += __shfl_xor(s, 4);
            s += __shfl_xor(s, 8);
            if (l15 == 0)
                lp[h * 16384 + b * 4096 + q * 64 + w * 16 + quad * 4 + r] = s;
        }
        unsigned short* ob = dst + (size_t)(b * 4096 + q * 64 + w * 16) * 512;
        #pragma unroll
        for (int ct = 0; ct < 32; ++ct)
            #pragma unroll
            for (int r = 0; r < 4; ++r)
                ob[(size_t)(quad * 4 + r) * 512 + ct * 16 + l15] = f2bf(o[ct][r]);
    }
}

// -------- combine: att[t][c] = (ph0+ph1)/(l0+l1), bf16 out --------
__global__ __launch_bounds__(256) void combine_kernel(
    const unsigned short* __restrict__ ph0, const unsigned short* __restrict__ ph1,
    const float* __restrict__ lp, unsigned short* __restrict__ att)
{
    int t = blockIdx.x * 4 + (threadIdx.x >> 6);
    int lane = threadIdx.x & 63;
    float inv = 1.0f / (lp[t] + lp[16384 + t]);
    const ushort4* pa = (const ushort4*)(ph0 + (size_t)t * 512 + lane * 8);
    const ushort4* pb = (const ushort4*)(ph1 + (size_t)t * 512 + lane * 8);
    ushort4* po = (ushort4*)(att + (size_t)t * 512 + lane * 8);
    #pragma unroll
    for (int i = 0; i < 2; ++i) {
        ushort4 a = pa[i], b = pb[i];
        po[i] = make_ushort4(
            f2bf((bf2f(a.x) + bf2f(b.x)) * inv),
            f2bf((bf2f(a.y) + bf2f(b.y)) * inv),
            f2bf((bf2f(a.z) + bf2f(b.z)) * inv),
            f2bf((bf2f(a.w) + bf2f(b.w)) * inv));
    }
}

extern "C" void kernel_launch(void* const* d_in, const int* in_sizes, int n_in,
                              void* d_out, int out_size, void* d_ws, size_t ws_size,
                              hipStream_t stream)
{
    const float* x     = (const float*)d_in[0];
    // d_in[1] = causal mask (tril ones) — causality applied analytically, not read
    const float* gamma = (const float*)d_in[2];
    const float* beta  = (const float*)d_in[3];
    const float* Wqkv  = (const float*)d_in[4];
    const float* Wproj = (const float*)d_in[5];
    float* out = (float*)d_out;

    char* ws = (char*)d_ws;
    unsigned short* qk     = (unsigned short*)(ws);              // 16384x1024 bf16 (32 MB)
    unsigned short* vraw   = (unsigned short*)(ws + 33554432);   // 16384x512 bf16 (16 MB)
    unsigned short* vtp    = (unsigned short*)(ws + 50331648);   // packed Vt (16 MB); att later
    unsigned short* xn     = (unsigned short*)(ws + 67108864);   // LN out (16 MB); ph0 later
    unsigned short* wqkvT  = (unsigned short*)(ws + 83886080);   // 1536x512 bf16; lp later
    unsigned short* wprojT = (unsigned short*)(ws + 85458944);   // 512x512 bf16
    unsigned short* ph0    = xn;    // dead after QKV GEMMs
    unsigned short* ph1    = vraw;  // dead after transpose_v
    float*          lp     = (float*)wqkvT;  // dead after QKV GEMMs (128 KB)
    unsigned short* att    = vtp;   // dead after attn

    ln_bf16_kernel<<<4096, 256, 0, stream>>>(x, gamma, beta, xn, 16384);
    transpose_w<<<dim3(8, 24), 256, 0, stream>>>(Wqkv, wqkvT, 512, 1536);
    transpose_w<<<dim3(8, 8), 256, 0, stream>>>(Wproj, wprojT, 512, 512);
    // QKV projection: Q|K -> qk (ldc 1024), V -> vraw (ldc 512)
    gemm_bt<<<dim3(128, 8), 256, 0, stream>>>(xn, wqkvT, qk,
                                              16384, 1024, 512, 512, 512, 1024, 1);
    gemm_bt<<<dim3(128, 4), 256, 0, stream>>>(xn, wqkvT + 1024 * 512, vraw,
                                              16384, 512, 512, 512, 512, 512, 1);
    transpose_v<<<dim3(64, 8, 4), 256, 0, stream>>>(vraw, vtp);
    attn_kernel<<<256, 256, 0, stream>>>(qk, vtp, ph0, ph1, lp);
    combine_kernel<<<4096, 256, 0, stream>>>(ph0, ph1, lp, att);
    gemm_bt<<<dim3(128, 4), 256, 0, stream>>>(att, wprojT, out,
                                              16384, 512, 512, 512, 512, 512, 0);
}

// Round 6
// 403.480 us; speedup vs baseline: 1.9121x; 1.9121x over previous
//
#include <hip/hip_runtime.h>

typedef short bf16x8 __attribute__((ext_vector_type(8)));
typedef float f32x4 __attribute__((ext_vector_type(4)));

#define AS1 __attribute__((address_space(1)))
#define AS3 __attribute__((address_space(3)))

// async global->LDS, 16B per lane. LDS dest is wave-uniform base + lane*16.
__device__ __forceinline__ void async16(const void* g, void* l) {
    __builtin_amdgcn_global_load_lds((AS1 unsigned*)(unsigned long long)g,
                                     (AS3 unsigned*)l, 16, 0, 0);
}

__device__ __forceinline__ unsigned short f2bf(float f) {
    unsigned u = __builtin_bit_cast(unsigned, f);
    u += 0x7fffu + ((u >> 16) & 1u);   // RNE
    return (unsigned short)(u >> 16);
}
__device__ __forceinline__ float bf2f(unsigned short s) {
    unsigned u = ((unsigned)s) << 16;
    return __builtin_bit_cast(float, u);
}

// ---------------- LayerNorm + bf16 cast: one wave per row of 512 ----------------
__global__ __launch_bounds__(256) void ln_bf16_kernel(
    const float* __restrict__ x, const float* __restrict__ gamma,
    const float* __restrict__ beta, unsigned short* __restrict__ xn, int nrows)
{
    int row = blockIdx.x * 4 + (threadIdx.x >> 6);
    int lane = threadIdx.x & 63;
    if (row >= nrows) return;
    const float4* xr = (const float4*)(x + (size_t)row * 512);
    float4 a = xr[lane], b = xr[lane + 64];
    float s = a.x + a.y + a.z + a.w + b.x + b.y + b.z + b.w;
    #pragma unroll
    for (int m = 1; m < 64; m <<= 1) s += __shfl_xor(s, m);
    float mu = s * (1.0f / 512.0f);
    float dx[8] = {a.x - mu, a.y - mu, a.z - mu, a.w - mu,
                   b.x - mu, b.y - mu, b.z - mu, b.w - mu};
    float ss = 0.f;
    #pragma unroll
    for (int i = 0; i < 8; ++i) ss += dx[i] * dx[i];
    #pragma unroll
    for (int m = 1; m < 64; m <<= 1) ss += __shfl_xor(ss, m);
    float rstd = rsqrtf(ss * (1.0f / 512.0f) + 1e-5f);
    const float4* gp = (const float4*)gamma;
    const float4* bp = (const float4*)beta;
    float4 g0 = gp[lane], g1 = gp[lane + 64], b0 = bp[lane], b1 = bp[lane + 64];
    float y[8];
    y[0] = dx[0] * rstd * g0.x + b0.x; y[1] = dx[1] * rstd * g0.y + b0.y;
    y[2] = dx[2] * rstd * g0.z + b0.z; y[3] = dx[3] * rstd * g0.w + b0.w;
    y[4] = dx[4] * rstd * g1.x + b1.x; y[5] = dx[5] * rstd * g1.y + b1.y;
    y[6] = dx[6] * rstd * g1.z + b1.z; y[7] = dx[7] * rstd * g1.w + b1.w;
    ushort4* orow = (ushort4*)(xn + (size_t)row * 512);
    orow[lane]      = make_ushort4(f2bf(y[0]), f2bf(y[1]), f2bf(y[2]), f2bf(y[3]));
    orow[lane + 64] = make_ushort4(f2bf(y[4]), f2bf(y[5]), f2bf(y[6]), f2bf(y[7]));
}

// ------------- fp32 [R][C] -> bf16 transposed [C][R] (for weights) -------------
__global__ __launch_bounds__(256) void transpose_w(
    const float* __restrict__ in, unsigned short* __restrict__ outT, int R, int Cd)
{
    __shared__ float tile[64][65];
    int r0 = blockIdx.x * 64, c0 = blockIdx.y * 64;
    int lr = threadIdx.x >> 6, lc = threadIdx.x & 63;
    #pragma unroll
    for (int i = 0; i < 16; ++i) {
        int r = i * 4 + lr;
        tile[r][lc] = in[(size_t)(r0 + r) * Cd + c0 + lc];
    }
    __syncthreads();
    #pragma unroll
    for (int i = 0; i < 16; ++i) {
        int r = i * 4 + lr;
        outT[(size_t)(c0 + r) * R + r0 + lc] = f2bf(tile[lc][r]);
    }
}

// ---- vraw[b*4096+t][512] -> tile-packed, BANK-SWIZZLED Vt panels ----
// Panel (b, jt=t/32): 2048 chunks of 8 bf16. Chunk (c, x=(t%32)/8) stored at
// slot c*4 + ((x ^ (c>>1)) & 3). Linear DMA staging then gives 2-way-max bank
// conflicts for PV fragment reads.
__global__ __launch_bounds__(256) void transpose_v(
    const unsigned short* __restrict__ vraw, unsigned short* __restrict__ vtp)
{
    __shared__ unsigned short tile[64][72];
    int b = blockIdx.z;
    int t0 = blockIdx.x * 64, c0 = blockIdx.y * 64;
    int lr = threadIdx.x >> 6, lc = threadIdx.x & 63;
    const unsigned short* src = vraw + (size_t)(b * 4096 + t0) * 512 + c0;
    #pragma unroll
    for (int i = 0; i < 16; ++i) {
        int r = i * 4 + lr;
        tile[r][lc] = src[(size_t)r * 512 + lc];   // tile[t_local][c_local]
    }
    __syncthreads();
    #pragma unroll
    for (int i = 0; i < 16; ++i) {
        int r = i * 4 + lr;                        // c_local
        int c = c0 + r;
        int jt = (t0 >> 5) + (lc >> 5);
        int tl = lc & 31;
        int x = tl >> 3;
        int slot = c * 4 + ((x ^ (c >> 1)) & 3);
        vtp[((size_t)(b * 128 + jt)) * 16384 + slot * 8 + (tl & 7)] = tile[lc][r];
    }
}

// ---------------- GEMM: C[M,N] = A[M,K] * Bt[N,K]^T, bf16 MFMA ----------------
__global__ __launch_bounds__(256) void gemm_bt(
    const unsigned short* __restrict__ A, const unsigned short* __restrict__ Bt,
    void* __restrict__ Cp, int M, int N, int K, int lda, int ldb, int ldc, int outBf16)
{
    __shared__ unsigned short As[128 * 64];
    __shared__ unsigned short Bs[128 * 64];
    const int tid = threadIdx.x;
    const int w = tid >> 6, lane = tid & 63, quad = lane >> 4, l15 = lane & 15;
    const int wm = w >> 1, wn = w & 1;
    const size_t m0 = (size_t)blockIdx.x * 128, n0 = (size_t)blockIdx.y * 128;
    f32x4 zero = {0.f, 0.f, 0.f, 0.f};
    f32x4 acc[4][4];
    #pragma unroll
    for (int i = 0; i < 4; ++i)
        #pragma unroll
        for (int j = 0; j < 4; ++j) acc[i][j] = zero;

    for (int k0 = 0; k0 < K; k0 += 64) {
        __syncthreads();
        #pragma unroll
        for (int r = 0; r < 4; ++r) {
            int s = r * 256 + w * 64 + lane;
            int row = s >> 3, x = s & 7, g = x ^ (row & 7);
            async16(A + (m0 + row) * lda + k0 + g * 8,
                    (char*)As + (size_t)(r * 256 + w * 64) * 16);
        }
        #pragma unroll
        for (int r = 0; r < 4; ++r) {
            int s = r * 256 + w * 64 + lane;
            int row = s >> 3, x = s & 7, g = x ^ (row & 7);
            async16(Bt + (n0 + row) * ldb + k0 + g * 8,
                    (char*)Bs + (size_t)(r * 256 + w * 64) * 16);
        }
        __syncthreads();
        #pragma unroll
        for (int ks = 0; ks < 2; ++ks) {
            bf16x8 af[4], bf[4];
            int cc = ks * 4 + quad;
            #pragma unroll
            for (int mt = 0; mt < 4; ++mt) {
                int row = wm * 64 + mt * 16 + l15;
                int x = cc ^ (row & 7);
                af[mt] = *(const bf16x8*)(As + row * 64 + x * 8);
            }
            #pragma unroll
            for (int nt = 0; nt < 4; ++nt) {
                int row = wn * 64 + nt * 16 + l15;
                int x = cc ^ (row & 7);
                bf[nt] = *(const bf16x8*)(Bs + row * 64 + x * 8);
            }
            #pragma unroll
            for (int mt = 0; mt < 4; ++mt)
                #pragma unroll
                for (int nt = 0; nt < 4; ++nt)
                    acc[mt][nt] = __builtin_amdgcn_mfma_f32_16x16x32_bf16(
                        af[mt], bf[nt], acc[mt][nt], 0, 0, 0);
        }
    }
    #pragma unroll
    for (int mt = 0; mt < 4; ++mt)
        #pragma unroll
        for (int nt = 0; nt < 4; ++nt)
            #pragma unroll
            for (int r = 0; r < 4; ++r) {
                size_t grow = m0 + wm * 64 + mt * 16 + quad * 4 + r;
                size_t gcol = n0 + wn * 64 + nt * 16 + l15;
                float v = acc[mt][nt][r];
                if (outBf16) ((unsigned short*)Cp)[grow * ldc + gcol] = f2bf(v);
                else         ((float*)Cp)[grow * ldc + gcol] = v;
            }
}

// ---------------- Flash attention v6: q64/4-wave, ROUND-4 split restored ----------------
// q-tile 64 rows => causal j-range is [0, 2q+2) 32-wide tiles (NOT q+1 -- round-5 bug).
// Block (b, qa, h): jobs q in {qa, 63-qa}; h=0 -> [0, q+1) (fully unmasked tiles),
// h=1 -> [q+1, 2q+2) (diagonal band, within-tile masking). Every block: exactly
// 65 j-tiles -> perfectly balanced. Unnormalized O (bf16) + row-sum l per half;
// combine kernel divides. Serial global_load_lds staging (no prefetch regs, no spill).
__global__ __launch_bounds__(256, 1) void attn_kernel(
    const unsigned short* __restrict__ qk,    // [b*4096+t][1024] : Q | K
    const unsigned short* __restrict__ vtp,   // swizzled panels [b][jt][2048 chunks]
    unsigned short* __restrict__ ph0, unsigned short* __restrict__ ph1,
    float* __restrict__ lp)                   // [2][16384]
{
    __shared__ unsigned short Ks[32 * 512];   // 32 KB, source-permuted chunks
    __shared__ unsigned short Vs[32 * 512];   // 32 KB, pre-swizzled panel copy
    __shared__ unsigned short Ps[4 * 16 * 40];// per-wave P, stride 40

    const int id = blockIdx.x;
    const int b = id & 3, p = id >> 2;
    const int qa = p >> 1, h = p & 1;

    const int tid = threadIdx.x, w = tid >> 6, lane = tid & 63;
    const int quad = lane >> 4, l15 = lane & 15;
    const float scale = 0.04419417382415922f;  // 1/sqrt(512)
    f32x4 zero = {0.f, 0.f, 0.f, 0.f};

    const unsigned short* kbase = qk + (size_t)(b * 4096) * 1024 + 512;
    const unsigned short* vbase = vtp + (size_t)(b * 128) * 16384;
    unsigned short* dst = h ? ph1 : ph0;

    #pragma unroll
    for (int job = 0; job < 2; ++job) {
        const int q = job ? (63 - qa) : qa;
        const int jt0 = h ? (q + 1) : 0;        // round-4 split: h=1 = diagonal band
        const int jtN = h ? (2 * q + 2) : (q + 1);

        // Q fragments: A[m=l15][k=quad*8+j], 16 k-steps of 32
        bf16x8 qf[16];
        {
            const unsigned short* qb =
                qk + (size_t)(b * 4096 + q * 64 + w * 16 + l15) * 1024;
            #pragma unroll
            for (int ks = 0; ks < 16; ++ks)
                qf[ks] = *(const bf16x8*)(qb + ks * 32 + quad * 8);
        }
        f32x4 o[32];
        #pragma unroll
        for (int i = 0; i < 32; ++i) o[i] = zero;
        float li[4] = {0.f, 0.f, 0.f, 0.f};

        for (int jt = jt0; jt < jtN; ++jt) {
            __syncthreads();   // all waves done reading previous tile
            {
                // K tile: 32 rows x 64 chunks, source-address permutation
                const unsigned short* kg = kbase + (size_t)jt * 32 * 1024;
                #pragma unroll
                for (int rnd = 0; rnd < 8; ++rnd) {
                    int s = rnd * 256 + tid;
                    int row = s >> 6, xx = s & 63;
                    int g = (xx & ~7) | ((xx ^ row) & 7);
                    async16(kg + (size_t)row * 1024 + g * 8,
                            (char*)Ks + (size_t)(rnd * 256 + w * 64) * 16);
                }
                // V tile: pre-swizzled panel, straight linear 32 KB copy
                const unsigned short* vg = vbase + (size_t)jt * 16384;
                #pragma unroll
                for (int rnd = 0; rnd < 8; ++rnd) {
                    int s = rnd * 256 + tid;
                    async16(vg + (size_t)s * 8,
                            (char*)Vs + (size_t)(rnd * 256 + w * 64) * 16);
                }
            }
            __syncthreads();   // staged tile visible (compiler adds vmcnt drain)

            // S = Q K^T  (64q x 32j; 16 q-rows per wave)
            f32x4 sa[2];
            sa[0] = zero; sa[1] = zero;
            #pragma unroll
            for (int ks = 0; ks < 16; ++ks) {
                int cc = ks * 4 + quad;
                #pragma unroll
                for (int nt = 0; nt < 2; ++nt) {
                    int jr = nt * 16 + l15;
                    int xg = (cc & ~7) | ((cc ^ jr) & 7);
                    bf16x8 kf = *(const bf16x8*)(Ks + jr * 512 + xg * 8);
                    sa[nt] = __builtin_amdgcn_mfma_f32_16x16x32_bf16(
                        qf[ks], kf, sa[nt], 0, 0, 0);
                }
            }
            // lane-local softmax accumulate (no max subtraction; scores ~N(0,1))
            const int trow = q * 64 + w * 16 + quad * 4;
            #pragma unroll
            for (int r = 0; r < 4; ++r) {
                #pragma unroll
                for (int nt = 0; nt < 2; ++nt) {
                    int col = jt * 32 + nt * 16 + l15;
                    float sv = sa[nt][r] * scale;
                    float pv = __expf(fminf(sv, 60.f));
                    if (col > trow + r) pv = 0.f;
                    li[r] += pv;
                    Ps[w * 640 + (quad * 4 + r) * 40 + nt * 16 + l15] = f2bf(pv);
                }
            }
            // O += P V : one k-step of 32 covers the j-tile
            bf16x8 pf = *(const bf16x8*)(Ps + w * 640 + l15 * 40 + quad * 8);
            #pragma unroll
            for (int ct = 0; ct < 32; ++ct) {
                int cch = ct * 16 + l15;
                int slot = cch * 4 + ((quad ^ (cch >> 1)) & 3);
                bf16x8 vf = *(const bf16x8*)(Vs + slot * 8);
                o[ct] = __builtin_amdgcn_mfma_f32_16x16x32_bf16(pf, vf, o[ct], 0, 0, 0);
            }
        }

        // row-sum reduction (16 lanes per quad-row) + unnormalized partial store
        #pragma unroll
        for (int r = 0; r < 4; ++r) {
            float s = li[r];
            s += __shfl_xor(s, 1);
            s += __shfl_xor(s, 2);
            s += __shfl_xor(s, 4);
            s += __shfl_xor(s, 8);
            if (l15 == 0)
                lp[h * 16384 + b * 4096 + q * 64 + w * 16 + quad * 4 + r] = s;
        }
        unsigned short* ob = dst + (size_t)(b * 4096 + q * 64 + w * 16) * 512;
        #pragma unroll
        for (int ct = 0; ct < 32; ++ct)
            #pragma unroll
            for (int r = 0; r < 4; ++r)
                ob[(size_t)(quad * 4 + r) * 512 + ct * 16 + l15] = f2bf(o[ct][r]);
    }
}

// -------- combine: att[t][c] = (ph0+ph1)/(l0+l1), bf16 out --------
__global__ __launch_bounds__(256) void combine_kernel(
    const unsigned short* __restrict__ ph0, const unsigned short* __restrict__ ph1,
    const float* __restrict__ lp, unsigned short* __restrict__ att)
{
    int t = blockIdx.x * 4 + (threadIdx.x >> 6);
    int lane = threadIdx.x & 63;
    float inv = 1.0f / (lp[t] + lp[16384 + t]);
    const ushort4* pa = (const ushort4*)(ph0 + (size_t)t * 512 + lane * 8);
    const ushort4* pb = (const ushort4*)(ph1 + (size_t)t * 512 + lane * 8);
    ushort4* po = (ushort4*)(att + (size_t)t * 512 + lane * 8);
    #pragma unroll
    for (int i = 0; i < 2; ++i) {
        ushort4 a = pa[i], b = pb[i];
        po[i] = make_ushort4(
            f2bf((bf2f(a.x) + bf2f(b.x)) * inv),
            f2bf((bf2f(a.y) + bf2f(b.y)) * inv),
            f2bf((bf2f(a.z) + bf2f(b.z)) * inv),
            f2bf((bf2f(a.w) + bf2f(b.w)) * inv));
    }
}

extern "C" void kernel_launch(void* const* d_in, const int* in_sizes, int n_in,
                              void* d_out, int out_size, void* d_ws, size_t ws_size,
                              hipStream_t stream)
{
    const float* x     = (const float*)d_in[0];
    // d_in[1] = causal mask (tril ones) — causality applied analytically, not read
    const float* gamma = (const float*)d_in[2];
    const float* beta  = (const float*)d_in[3];
    const float* Wqkv  = (const float*)d_in[4];
    const float* Wproj = (const float*)d_in[5];
    float* out = (float*)d_out;

    char* ws = (char*)d_ws;
    unsigned short* qk     = (unsigned short*)(ws);              // 16384x1024 bf16 (32 MB)
    unsigned short* vraw   = (unsigned short*)(ws + 33554432);   // 16384x512 bf16 (16 MB)
    unsigned short* vtp    = (unsigned short*)(ws + 50331648);   // packed Vt (16 MB); att later
    unsigned short* xn     = (unsigned short*)(ws + 67108864);   // LN out (16 MB); ph0 later
    unsigned short* wqkvT  = (unsigned short*)(ws + 83886080);   // 1536x512 bf16; lp later
    unsigned short* wprojT = (unsigned short*)(ws + 85458944);   // 512x512 bf16
    unsigned short* ph0    = xn;    // dead after QKV GEMMs
    unsigned short* ph1    = vraw;  // dead after transpose_v
    float*          lp     = (float*)wqkvT;  // dead after QKV GEMMs (128 KB)
    unsigned short* att    = vtp;   // dead after attn

    ln_bf16_kernel<<<4096, 256, 0, stream>>>(x, gamma, beta, xn, 16384);
    transpose_w<<<dim3(8, 24), 256, 0, stream>>>(Wqkv, wqkvT, 512, 1536);
    transpose_w<<<dim3(8, 8), 256, 0, stream>>>(Wproj, wprojT, 512, 512);
    // QKV projection: Q|K -> qk (ldc 1024), V -> vraw (ldc 512)
    gemm_bt<<<dim3(128, 8), 256, 0, stream>>>(xn, wqkvT, qk,
                                              16384, 1024, 512, 512, 512, 1024, 1);
    gemm_bt<<<dim3(128, 4), 256, 0, stream>>>(xn, wqkvT + 1024 * 512, vraw,
                                              16384, 512, 512, 512, 512, 512, 1);
    transpose_v<<<dim3(64, 8, 4), 256, 0, stream>>>(vraw, vtp);
    attn_kernel<<<256, 256, 0, stream>>>(qk, vtp, ph0, ph1, lp);
    combine_kernel<<<4096, 256, 0, stream>>>(ph0, ph1, lp, att);
    gemm_bt<<<dim3(128, 4), 256, 0, stream>>>(att, wprojT, out,
                                              16384, 512, 512, 512, 512, 512, 0);
}

// Round 7
// 397.871 us; speedup vs baseline: 1.9391x; 1.0141x over previous
//
#include <hip/hip_runtime.h>

typedef short bf16x8 __attribute__((ext_vector_type(8)));
typedef float f32x4 __attribute__((ext_vector_type(4)));

#define AS1 __attribute__((address_space(1)))
#define AS3 __attribute__((address_space(3)))

// async global->LDS, 16B per lane. LDS dest is wave-uniform base + lane*16.
__device__ __forceinline__ void async16(const void* g, void* l) {
    __builtin_amdgcn_global_load_lds((AS1 unsigned*)(unsigned long long)g,
                                     (AS3 unsigned*)l, 16, 0, 0);
}

__device__ __forceinline__ unsigned short f2bf(float f) {
    unsigned u = __builtin_bit_cast(unsigned, f);
    u += 0x7fffu + ((u >> 16) & 1u);   // RNE
    return (unsigned short)(u >> 16);
}
__device__ __forceinline__ float bf2f(unsigned short s) {
    unsigned u = ((unsigned)s) << 16;
    return __builtin_bit_cast(float, u);
}

// ---------------- LayerNorm + bf16 cast: one wave per row of 512 ----------------
__global__ __launch_bounds__(256) void ln_bf16_kernel(
    const float* __restrict__ x, const float* __restrict__ gamma,
    const float* __restrict__ beta, unsigned short* __restrict__ xn, int nrows)
{
    int row = blockIdx.x * 4 + (threadIdx.x >> 6);
    int lane = threadIdx.x & 63;
    if (row >= nrows) return;
    const float4* xr = (const float4*)(x + (size_t)row * 512);
    float4 a = xr[lane], b = xr[lane + 64];
    float s = a.x + a.y + a.z + a.w + b.x + b.y + b.z + b.w;
    #pragma unroll
    for (int m = 1; m < 64; m <<= 1) s += __shfl_xor(s, m);
    float mu = s * (1.0f / 512.0f);
    float dx[8] = {a.x - mu, a.y - mu, a.z - mu, a.w - mu,
                   b.x - mu, b.y - mu, b.z - mu, b.w - mu};
    float ss = 0.f;
    #pragma unroll
    for (int i = 0; i < 8; ++i) ss += dx[i] * dx[i];
    #pragma unroll
    for (int m = 1; m < 64; m <<= 1) ss += __shfl_xor(ss, m);
    float rstd = rsqrtf(ss * (1.0f / 512.0f) + 1e-5f);
    const float4* gp = (const float4*)gamma;
    const float4* bp = (const float4*)beta;
    float4 g0 = gp[lane], g1 = gp[lane + 64], b0 = bp[lane], b1 = bp[lane + 64];
    float y[8];
    y[0] = dx[0] * rstd * g0.x + b0.x; y[1] = dx[1] * rstd * g0.y + b0.y;
    y[2] = dx[2] * rstd * g0.z + b0.z; y[3] = dx[3] * rstd * g0.w + b0.w;
    y[4] = dx[4] * rstd * g1.x + b1.x; y[5] = dx[5] * rstd * g1.y + b1.y;
    y[6] = dx[6] * rstd * g1.z + b1.z; y[7] = dx[7] * rstd * g1.w + b1.w;
    ushort4* orow = (ushort4*)(xn + (size_t)row * 512);
    orow[lane]      = make_ushort4(f2bf(y[0]), f2bf(y[1]), f2bf(y[2]), f2bf(y[3]));
    orow[lane + 64] = make_ushort4(f2bf(y[4]), f2bf(y[5]), f2bf(y[6]), f2bf(y[7]));
}

// ------------- fp32 [R][C] -> bf16 transposed [C][R] (for weights) -------------
__global__ __launch_bounds__(256) void transpose_w(
    const float* __restrict__ in, unsigned short* __restrict__ outT, int R, int Cd)
{
    __shared__ float tile[64][65];
    int r0 = blockIdx.x * 64, c0 = blockIdx.y * 64;
    int lr = threadIdx.x >> 6, lc = threadIdx.x & 63;
    #pragma unroll
    for (int i = 0; i < 16; ++i) {
        int r = i * 4 + lr;
        tile[r][lc] = in[(size_t)(r0 + r) * Cd + c0 + lc];
    }
    __syncthreads();
    #pragma unroll
    for (int i = 0; i < 16; ++i) {
        int r = i * 4 + lr;
        outT[(size_t)(c0 + r) * R + r0 + lc] = f2bf(tile[lc][r]);
    }
}

// ---- vraw[b*4096+t][512] -> tile-packed, BANK-SWIZZLED Vt panels ----
// Panel (b, jt=t/32): 2048 chunks of 8 bf16. Chunk (c, x=(t%32)/8) stored at
// slot c*4 + ((x ^ (c>>1)) & 3). Linear DMA staging then gives 2-way-max bank
// conflicts for PV fragment reads.
__global__ __launch_bounds__(256) void transpose_v(
    const unsigned short* __restrict__ vraw, unsigned short* __restrict__ vtp)
{
    __shared__ unsigned short tile[64][72];
    int b = blockIdx.z;
    int t0 = blockIdx.x * 64, c0 = blockIdx.y * 64;
    int lr = threadIdx.x >> 6, lc = threadIdx.x & 63;
    const unsigned short* src = vraw + (size_t)(b * 4096 + t0) * 512 + c0;
    #pragma unroll
    for (int i = 0; i < 16; ++i) {
        int r = i * 4 + lr;
        tile[r][lc] = src[(size_t)r * 512 + lc];   // tile[t_local][c_local]
    }
    __syncthreads();
    #pragma unroll
    for (int i = 0; i < 16; ++i) {
        int r = i * 4 + lr;                        // c_local
        int c = c0 + r;
        int jt = (t0 >> 5) + (lc >> 5);
        int tl = lc & 31;
        int x = tl >> 3;
        int slot = c * 4 + ((x ^ (c >> 1)) & 3);
        vtp[((size_t)(b * 128 + jt)) * 16384 + slot * 8 + (tl & 7)] = tile[lc][r];
    }
}

// ---------------- GEMM: C[M,N] = A[M,K] * Bt[N,K]^T, bf16 MFMA ----------------
__global__ __launch_bounds__(256) void gemm_bt(
    const unsigned short* __restrict__ A, const unsigned short* __restrict__ Bt,
    void* __restrict__ Cp, int M, int N, int K, int lda, int ldb, int ldc, int outBf16)
{
    __shared__ unsigned short As[128 * 64];
    __shared__ unsigned short Bs[128 * 64];
    const int tid = threadIdx.x;
    const int w = tid >> 6, lane = tid & 63, quad = lane >> 4, l15 = lane & 15;
    const int wm = w >> 1, wn = w & 1;
    const size_t m0 = (size_t)blockIdx.x * 128, n0 = (size_t)blockIdx.y * 128;
    f32x4 zero = {0.f, 0.f, 0.f, 0.f};
    f32x4 acc[4][4];
    #pragma unroll
    for (int i = 0; i < 4; ++i)
        #pragma unroll
        for (int j = 0; j < 4; ++j) acc[i][j] = zero;

    for (int k0 = 0; k0 < K; k0 += 64) {
        __syncthreads();
        #pragma unroll
        for (int r = 0; r < 4; ++r) {
            int s = r * 256 + w * 64 + lane;
            int row = s >> 3, x = s & 7, g = x ^ (row & 7);
            async16(A + (m0 + row) * lda + k0 + g * 8,
                    (char*)As + (size_t)(r * 256 + w * 64) * 16);
        }
        #pragma unroll
        for (int r = 0; r < 4; ++r) {
            int s = r * 256 + w * 64 + lane;
            int row = s >> 3, x = s & 7, g = x ^ (row & 7);
            async16(Bt + (n0 + row) * ldb + k0 + g * 8,
                    (char*)Bs + (size_t)(r * 256 + w * 64) * 16);
        }
        __syncthreads();
        #pragma unroll
        for (int ks = 0; ks < 2; ++ks) {
            bf16x8 af[4], bf[4];
            int cc = ks * 4 + quad;
            #pragma unroll
            for (int mt = 0; mt < 4; ++mt) {
                int row = wm * 64 + mt * 16 + l15;
                int x = cc ^ (row & 7);
                af[mt] = *(const bf16x8*)(As + row * 64 + x * 8);
            }
            #pragma unroll
            for (int nt = 0; nt < 4; ++nt) {
                int row = wn * 64 + nt * 16 + l15;
                int x = cc ^ (row & 7);
                bf[nt] = *(const bf16x8*)(Bs + row * 64 + x * 8);
            }
            #pragma unroll
            for (int mt = 0; mt < 4; ++mt)
                #pragma unroll
                for (int nt = 0; nt < 4; ++nt)
                    acc[mt][nt] = __builtin_amdgcn_mfma_f32_16x16x32_bf16(
                        af[mt], bf[nt], acc[mt][nt], 0, 0, 0);
        }
    }
    #pragma unroll
    for (int mt = 0; mt < 4; ++mt)
        #pragma unroll
        for (int nt = 0; nt < 4; ++nt)
            #pragma unroll
            for (int r = 0; r < 4; ++r) {
                size_t grow = m0 + wm * 64 + mt * 16 + quad * 4 + r;
                size_t gcol = n0 + wn * 64 + nt * 16 + l15;
                float v = acc[mt][nt][r];
                if (outBf16) ((unsigned short*)Cp)[grow * ldc + gcol] = f2bf(v);
                else         ((float*)Cp)[grow * ldc + gcol] = v;
            }
}

// ---------------- Flash attention v7: 2 blocks/CU via 64KB LDS + 512 blocks ----------------
// One (b, q, h) job per block; h=0 -> [0,q+1), h=1 -> [q+1,2q+2) -- both q+1 tiles.
// id map: CU c (= id&255) gets hi=0 job (q=c>>2, h=0: (c>>2)+1 tiles) and hi=1 job
// (q=63-(c>>2), h=1: 64-(c>>2) tiles) -> 65 tiles/CU, co-resident (2x64KB LDS packs
// per m132). Independent blocks overlap each other's staging drains.
// P buffer overlaid into Ks: extra barrier after QK^T makes it safe and keeps 64KB.
__global__ __launch_bounds__(256, 2) void attn_kernel(
    const unsigned short* __restrict__ qk,    // [b*4096+t][1024] : Q | K
    const unsigned short* __restrict__ vtp,   // swizzled panels [b][jt][2048 chunks]
    unsigned short* __restrict__ ph0, unsigned short* __restrict__ ph1,
    float* __restrict__ lp)                   // [2][16384]
{
    __shared__ unsigned short Ks[32 * 512];   // 32 KB, source-permuted chunks
    __shared__ unsigned short Vs[32 * 512];   // 32 KB, pre-swizzled panel copy
    unsigned short* Ps = Ks;                  // P overlaid (5 KB); safe after QK^T barrier

    const int id = blockIdx.x;
    const int cu = id & 255, hi = id >> 8;
    const int b = cu & 3;
    const int q = hi ? (63 - (cu >> 2)) : (cu >> 2);
    const int h = hi;

    const int jt0 = h ? (q + 1) : 0;
    const int jtN = h ? (2 * q + 2) : (q + 1);

    const int tid = threadIdx.x, w = tid >> 6, lane = tid & 63;
    const int quad = lane >> 4, l15 = lane & 15;
    const float scale = 0.04419417382415922f;  // 1/sqrt(512)
    f32x4 zero = {0.f, 0.f, 0.f, 0.f};

    const unsigned short* kbase = qk + (size_t)(b * 4096) * 1024 + 512;
    const unsigned short* vbase = vtp + (size_t)(b * 128) * 16384;
    unsigned short* dst = h ? ph1 : ph0;

    // Q fragments: A[m=l15][k=quad*8+j], 16 k-steps of 32
    bf16x8 qf[16];
    {
        const unsigned short* qb =
            qk + (size_t)(b * 4096 + q * 64 + w * 16 + l15) * 1024;
        #pragma unroll
        for (int ks = 0; ks < 16; ++ks)
            qf[ks] = *(const bf16x8*)(qb + ks * 32 + quad * 8);
    }
    f32x4 o[32];
    #pragma unroll
    for (int i = 0; i < 32; ++i) o[i] = zero;
    float li[4] = {0.f, 0.f, 0.f, 0.f};

    for (int jt = jt0; jt < jtN; ++jt) {
        __syncthreads();   // all waves done with previous tile's K(P) and V reads
        {
            // K tile: 32 rows x 64 chunks, source-address permutation
            const unsigned short* kg = kbase + (size_t)jt * 32 * 1024;
            #pragma unroll
            for (int rnd = 0; rnd < 8; ++rnd) {
                int s = rnd * 256 + tid;
                int row = s >> 6, xx = s & 63;
                int g = (xx & ~7) | ((xx ^ row) & 7);
                async16(kg + (size_t)row * 1024 + g * 8,
                        (char*)Ks + (size_t)(rnd * 256 + w * 64) * 16);
            }
            // V tile: pre-swizzled panel, straight linear 32 KB copy
            const unsigned short* vg = vbase + (size_t)jt * 16384;
            #pragma unroll
            for (int rnd = 0; rnd < 8; ++rnd) {
                int s = rnd * 256 + tid;
                async16(vg + (size_t)s * 8,
                        (char*)Vs + (size_t)(rnd * 256 + w * 64) * 16);
            }
        }
        __syncthreads();   // staged tile visible (compiler adds vmcnt drain)

        // S = Q K^T  (64q x 32j; 16 q-rows per wave)
        f32x4 sa[2];
        sa[0] = zero; sa[1] = zero;
        #pragma unroll
        for (int ks = 0; ks < 16; ++ks) {
            int cc = ks * 4 + quad;
            #pragma unroll
            for (int nt = 0; nt < 2; ++nt) {
                int jr = nt * 16 + l15;
                int xg = (cc & ~7) | ((cc ^ jr) & 7);
                bf16x8 kf = *(const bf16x8*)(Ks + jr * 512 + xg * 8);
                sa[nt] = __builtin_amdgcn_mfma_f32_16x16x32_bf16(
                    qf[ks], kf, sa[nt], 0, 0, 0);
            }
        }
        // lane-local softmax into registers (no max subtraction; scores ~N(0,1))
        const int trow = q * 64 + w * 16 + quad * 4;
        unsigned short pb[4][2];
        #pragma unroll
        for (int r = 0; r < 4; ++r) {
            #pragma unroll
            for (int nt = 0; nt < 2; ++nt) {
                int col = jt * 32 + nt * 16 + l15;
                float sv = sa[nt][r] * scale;
                float pv = __expf(fminf(sv, 60.f));
                if (col > trow + r) pv = 0.f;
                li[r] += pv;
                pb[r][nt] = f2bf(pv);
            }
        }
        __syncthreads();   // all waves done reading Ks -> safe to overlay P
        #pragma unroll
        for (int r = 0; r < 4; ++r)
            #pragma unroll
            for (int nt = 0; nt < 2; ++nt)
                Ps[w * 640 + (quad * 4 + r) * 40 + nt * 16 + l15] = pb[r][nt];

        // O += P V : one k-step of 32 covers the j-tile
        bf16x8 pf = *(const bf16x8*)(Ps + w * 640 + l15 * 40 + quad * 8);
        #pragma unroll
        for (int ct = 0; ct < 32; ++ct) {
            int cch = ct * 16 + l15;
            int slot = cch * 4 + ((quad ^ (cch >> 1)) & 3);
            bf16x8 vf = *(const bf16x8*)(Vs + slot * 8);
            o[ct] = __builtin_amdgcn_mfma_f32_16x16x32_bf16(pf, vf, o[ct], 0, 0, 0);
        }
    }

    // row-sum reduction (16 lanes per quad-row) + unnormalized partial store
    #pragma unroll
    for (int r = 0; r < 4; ++r) {
        float s = li[r];
        s += __shfl_xor(s, 1);
        s += __shfl_xor(s, 2);
        s += __shfl_xor(s, 4);
        s += __shfl_xor(s, 8);
        if (l15 == 0)
            lp[h * 16384 + b * 4096 + q * 64 + w * 16 + quad * 4 + r] = s;
    }
    unsigned short* ob = dst + (size_t)(b * 4096 + q * 64 + w * 16) * 512;
    #pragma unroll
    for (int ct = 0; ct < 32; ++ct)
        #pragma unroll
        for (int r = 0; r < 4; ++r)
            ob[(size_t)(quad * 4 + r) * 512 + ct * 16 + l15] = f2bf(o[ct][r]);
}

// -------- combine: att[t][c] = (ph0+ph1)/(l0+l1), bf16 out --------
__global__ __launch_bounds__(256) void combine_kernel(
    const unsigned short* __restrict__ ph0, const unsigned short* __restrict__ ph1,
    const float* __restrict__ lp, unsigned short* __restrict__ att)
{
    int t = blockIdx.x * 4 + (threadIdx.x >> 6);
    int lane = threadIdx.x & 63;
    float inv = 1.0f / (lp[t] + lp[16384 + t]);
    const ushort4* pa = (const ushort4*)(ph0 + (size_t)t * 512 + lane * 8);
    const ushort4* pb = (const ushort4*)(ph1 + (size_t)t * 512 + lane * 8);
    ushort4* po = (ushort4*)(att + (size_t)t * 512 + lane * 8);
    #pragma unroll
    for (int i = 0; i < 2; ++i) {
        ushort4 a = pa[i], b = pb[i];
        po[i] = make_ushort4(
            f2bf((bf2f(a.x) + bf2f(b.x)) * inv),
            f2bf((bf2f(a.y) + bf2f(b.y)) * inv),
            f2bf((bf2f(a.z) + bf2f(b.z)) * inv),
            f2bf((bf2f(a.w) + bf2f(b.w)) * inv));
    }
}

extern "C" void kernel_launch(void* const* d_in, const int* in_sizes, int n_in,
                              void* d_out, int out_size, void* d_ws, size_t ws_size,
                              hipStream_t stream)
{
    const float* x     = (const float*)d_in[0];
    // d_in[1] = causal mask (tril ones) — causality applied analytically, not read
    const float* gamma = (const float*)d_in[2];
    const float* beta  = (const float*)d_in[3];
    const float* Wqkv  = (const float*)d_in[4];
    const float* Wproj = (const float*)d_in[5];
    float* out = (float*)d_out;

    char* ws = (char*)d_ws;
    unsigned short* qk     = (unsigned short*)(ws);              // 16384x1024 bf16 (32 MB)
    unsigned short* vraw   = (unsigned short*)(ws + 33554432);   // 16384x512 bf16 (16 MB)
    unsigned short* vtp    = (unsigned short*)(ws + 50331648);   // packed Vt (16 MB); att later
    unsigned short* xn     = (unsigned short*)(ws + 67108864);   // LN out (16 MB); ph0 later
    unsigned short* wqkvT  = (unsigned short*)(ws + 83886080);   // 1536x512 bf16; lp later
    unsigned short* wprojT = (unsigned short*)(ws + 85458944);   // 512x512 bf16
    unsigned short* ph0    = xn;    // dead after QKV GEMMs
    unsigned short* ph1    = vraw;  // dead after transpose_v
    float*          lp     = (float*)wqkvT;  // dead after QKV GEMMs (128 KB)
    unsigned short* att    = vtp;   // dead after attn

    ln_bf16_kernel<<<4096, 256, 0, stream>>>(x, gamma, beta, xn, 16384);
    transpose_w<<<dim3(8, 24), 256, 0, stream>>>(Wqkv, wqkvT, 512, 1536);
    transpose_w<<<dim3(8, 8), 256, 0, stream>>>(Wproj, wprojT, 512, 512);
    // QKV projection: Q|K -> qk (ldc 1024), V -> vraw (ldc 512)
    gemm_bt<<<dim3(128, 8), 256, 0, stream>>>(xn, wqkvT, qk,
                                              16384, 1024, 512, 512, 512, 1024, 1);
    gemm_bt<<<dim3(128, 4), 256, 0, stream>>>(xn, wqkvT + 1024 * 512, vraw,
                                              16384, 512, 512, 512, 512, 512, 1);
    transpose_v<<<dim3(64, 8, 4), 256, 0, stream>>>(vraw, vtp);
    attn_kernel<<<512, 256, 0, stream>>>(qk, vtp, ph0, ph1, lp);
    combine_kernel<<<4096, 256, 0, stream>>>(ph0, ph1, lp, att);
    gemm_bt<<<dim3(128, 4), 256, 0, stream>>>(att, wprojT, out,
                                              16384, 512, 512, 512, 512, 512, 0);
}